// Round 6
// baseline (308.285 us; speedup 1.0000x reference)
//
#include <hip/hip_runtime.h>
#include <hip/hip_bf16.h>

#define C_DIM 100000
#define N_ROW 512
#define K_DIM 512
#define OUT_HALF 51200000  // N_ROW * C_DIM

#define SCALE_F 64.0f
#define ALPHA_F 0.1f
#define COS_M_F 0.87758256189037276f
#define SIN_M_F 0.47942553860420301f
#define THRESH_F (-0.87758256189037276f)
#define MM_F 0.23971276930210151f

// ws layout (bytes)
#define WS_ASW 0u
#define WS_TARGET 524288u
#define WS_CTM 526336u
#define WS_FTL 528384u
#define WS_TNEW 530432u
#define WS_INVN 532480u                       // 100352 f32 = 401408 B
#define WS_BSW 1048576ull
#define BSW_BYTES (1564ull * 65536ull)        // 1564 strips x 64 KiB
#define WS_NEED (WS_BSW + BSW_BYTES)

typedef __attribute__((ext_vector_type(8))) short short8;
typedef __attribute__((ext_vector_type(4))) short short4v;
typedef __attribute__((ext_vector_type(4))) float f32x4;
typedef __attribute__((ext_vector_type(2))) int i32x2;

static __device__ __forceinline__ unsigned short f2bf(float f) {
  union { float f; unsigned u; } x; x.f = f;
  unsigned r = x.u + 0x7fffu + ((x.u >> 16) & 1u);
  return (unsigned short)(r >> 16);
}

// ---------------------------------------------------------------------------
// N1: normalize embedding rows, write bf16 A in MFMA-fragment-ready layout.
// ---------------------------------------------------------------------------
__global__ __launch_bounds__(64) void prep_emb(const float* __restrict__ emb,
                                               unsigned short* __restrict__ Asw) {
  const int m = blockIdx.x;
  const int t = threadIdx.x;
  const float* row = emb + (size_t)m * K_DIM;
  float ss = 0.f;
#pragma unroll
  for (int d = 0; d < 8; ++d) { float v = row[t + 64 * d]; ss += v * v; }
#pragma unroll
  for (int off = 32; off > 0; off >>= 1) ss += __shfl_xor(ss, off, 64);
  const float inv = rsqrtf(ss);
  const int s = t >> 2, g = t & 3;
  short8 pack;
#pragma unroll
  for (int j = 0; j < 8; ++j) {
    int k = 32 * s + 4 * g + (j & 3) + 16 * (j >> 2);
    pack[j] = (short)f2bf(row[k] * inv);
  }
  size_t idx = ((size_t)(s * 32 + (m >> 4)) * 64 + (m & 15) + 16 * g) * 8;
  *(short8*)(Asw + idx) = pack;
}

// ---------------------------------------------------------------------------
// N3: per-row target logit in f32
// ---------------------------------------------------------------------------
__global__ __launch_bounds__(64) void target_k(const float* __restrict__ emb,
                                               const float* __restrict__ Kmat,
                                               const int* __restrict__ labels,
                                               float* __restrict__ target) {
  const int i = blockIdx.x;
  const int t = threadIdx.x;
  const int lab = labels[i];
  const float* row = emb + (size_t)i * K_DIM;
  float dot = 0.f, ess = 0.f, kss = 0.f;
#pragma unroll
  for (int d0 = 0; d0 < 8; ++d0) {
    int d = t + 64 * d0;
    float e = row[d];
    float k = Kmat[(size_t)d * C_DIM + lab];
    dot += e * k; ess += e * e; kss += k * k;
  }
#pragma unroll
  for (int off = 32; off > 0; off >>= 1) {
    dot += __shfl_xor(dot, off, 64);
    ess += __shfl_xor(ess, off, 64);
    kss += __shfl_xor(kss, off, 64);
  }
  if (t == 0) {
    float tg = dot * rsqrtf(ess) * rsqrtf(kss);
    tg = fminf(1.f, fmaxf(-1.f, tg));
    target[i] = tg;
  }
}

// ---------------------------------------------------------------------------
// N4: t_new, per-row cos_theta_m and final_target_logit
// ---------------------------------------------------------------------------
__global__ __launch_bounds__(512) void rowdata_k(const float* __restrict__ target,
                                                 const float* __restrict__ t_in,
                                                 float* __restrict__ ctm,
                                                 float* __restrict__ ftl,
                                                 float* __restrict__ tnew) {
  __shared__ float red[512];
  const int i = threadIdx.x;
  const float tg = target[i];
  red[i] = tg;
  __syncthreads();
  for (int s = 256; s > 0; s >>= 1) {
    if (i < s) red[i] += red[i + s];
    __syncthreads();
  }
  const float t_new = red[0] * (1.0f / 512.0f) * ALPHA_F + (1.f - ALPHA_F) * t_in[0];
  const float st = sqrtf(fmaxf(0.f, 1.f - tg * tg));
  const float cm = tg * COS_M_F - st * SIN_M_F;
  ctm[i] = cm;
  ftl[i] = (tg > THRESH_F) ? cm : (tg - MM_F);
  if (i == 0) tnew[0] = t_new;
}

// ---------------------------------------------------------------------------
// K1: column norms + f32->bf16 conversion into GEMM-ready swizzled layout.
// Bsw byte layout: [strip(64cols)][r>>5][cs=cl>>4][k=r&31][c=cl&15] bf16,
// i.e. strip*65536 + (r>>5)*4096 + (cl>>4)*1024 + (r&31)*32 + (cl&15)*2.
// Pure stream: read Kmat once (NT), write 102 MB bf16 (plain -> IC).
// ---------------------------------------------------------------------------
__global__ __launch_bounds__(512) void colnorm_convert(
    const float* __restrict__ Kmat, unsigned short* __restrict__ Bsw,
    float* __restrict__ invn_g) {
  __shared__ f32x4 red[8][64];
  const int t = threadIdx.x;
  const int q = t & 63;   // col quad within 256-col panel
  const int rg = t >> 6;  // 0..7: row group (owns rows rg*64 .. rg*64+63)
  const int c0 = blockIdx.x * 256;
  const int cg = c0 + q * 4;
  const bool cok = (cg < C_DIM);  // float4 fully in-bounds (C%4==0)
  char* const bbase = (char*)Bsw + (size_t)(cg >> 6) * 65536 +
                      (size_t)(((cg & 63) >> 4)) * 1024 + (size_t)((cg & 12) * 2);
  f32x4 ssq = (f32x4){0.f, 0.f, 0.f, 0.f};
#pragma unroll 4
  for (int i = 0; i < 64; ++i) {
    const int r = rg * 64 + i;  // sequential rows per wave
    f32x4 v = (f32x4){0.f, 0.f, 0.f, 0.f};
    if (cok)
      v = __builtin_nontemporal_load((const f32x4*)(Kmat + (size_t)r * C_DIM + cg));
    ssq += v * v;
    i32x2 p;
    p[0] = (int)((unsigned)f2bf(v[0]) | ((unsigned)f2bf(v[1]) << 16));
    p[1] = (int)((unsigned)f2bf(v[2]) | ((unsigned)f2bf(v[3]) << 16));
    *(i32x2*)(bbase + (size_t)((r >> 5) * 4096 + (r & 31) * 32)) = p;
  }
  red[rg][q] = ssq;
  __syncthreads();
  if (t < 64) {
    f32x4 s = red[0][t];
#pragma unroll
    for (int g = 1; g < 8; ++g) s += red[g][t];
    f32x4 iv;
#pragma unroll
    for (int j = 0; j < 4; ++j) iv[j] = rsqrtf(fmaxf(s[j], 1e-30f));
    *(f32x4*)&invn_g[c0 + t * 4] = iv;
  }
}

// ---------------------------------------------------------------------------
// K2: m97-pattern GEMM + fused epilogue. BM=512, BN=64, BK=64, 8 waves.
// B staged via global_load_lds_dwordx4 (1 instr/wave/step) from Bsw whose
// linear order == LDS tr-read layout. Inner loop has NO conversions and NO
// VGPR->LDS writes. Plain (non-NT) output stores.
// ---------------------------------------------------------------------------
#define STAGE(buf_, s_)                                                         \
  do {                                                                          \
    const char* _src = bs + ((size_t)(s_)*8192) + (size_t)wv * 1024 +           \
                       (size_t)lane * 16;                                       \
    __builtin_amdgcn_global_load_lds(                                           \
        (const __attribute__((address_space(1))) unsigned int*)_src,            \
        (__attribute__((address_space(3))) unsigned int*)&Kl[buf_][wv * 512],   \
        16, 0, 0);                                                              \
  } while (0)

__global__ __launch_bounds__(512) void gemm_bsw(
    const unsigned short* __restrict__ Bsw,
    const unsigned short* __restrict__ Asw,
    const float* __restrict__ invn_g,
    const float* __restrict__ ctm_a,
    const float* __restrict__ ftl_a,
    const float* __restrict__ tnew_p,
    const int* __restrict__ labels,
    float* __restrict__ out) {
  __shared__ unsigned short Kl[2][4096];  // 2 x 8 KiB (one BK=64 tile each)

  const int tid = threadIdx.x;
  const int wv = tid >> 6;
  const int lane = tid & 63;
  const int strip = blockIdx.x;
  const int c0 = strip * 64;
  const char* bs = (const char*)Bsw + (size_t)strip * 65536;

  f32x4 acc[4][4];
#pragma unroll
  for (int i = 0; i < 4; ++i)
#pragma unroll
    for (int j = 0; j < 4; ++j) acc[i][j] = (f32x4){0.f, 0.f, 0.f, 0.f};

  const unsigned klbase = (unsigned)(uintptr_t)&Kl[0][0];

  // prologue
  STAGE(0, 0);
  __syncthreads();

  for (int s = 0; s < 8; ++s) {
    const int buf = s & 1;
    if (s < 7) STAGE(buf ^ 1, s + 1);  // DMA for next tile, in flight all step

    // Y fragments (emb side) from pre-swizzled global (L2-resident)
    short8 Y[2][4];
#pragma unroll
    for (int kk = 0; kk < 2; ++kk)
#pragma unroll
      for (int ms = 0; ms < 4; ++ms)
        Y[kk][ms] = *(const short8*)(
            Asw + (size_t)(((2 * s + kk) * 32 + wv * 4 + ms) * 64 + lane) * 8);

#pragma unroll
    for (int kk = 0; kk < 2; ++kk) {
      short8 X[4];
      const unsigned base =
          klbase + (unsigned)(buf * 8192 + kk * 4096) + (unsigned)lane * 8;
#pragma unroll
      for (int cs = 0; cs < 4; ++cs) {
        i32x2 t0, t1;
        unsigned a = base + (unsigned)cs * 1024;
        asm volatile("ds_read_b64_tr_b16 %0, %2\n\t"
                     "ds_read_b64_tr_b16 %1, %2 offset:512"
                     : "=&v"(t0), "=&v"(t1)
                     : "v"(a));
        short4v lo = __builtin_bit_cast(short4v, t0);
        short4v hi = __builtin_bit_cast(short4v, t1);
        X[cs] = __builtin_shufflevector(lo, hi, 0, 1, 2, 3, 4, 5, 6, 7);
      }
      asm volatile("s_waitcnt lgkmcnt(0)" ::: "memory");
      __builtin_amdgcn_sched_barrier(0);
#pragma unroll
      for (int cs = 0; cs < 4; ++cs)
#pragma unroll
        for (int ms = 0; ms < 4; ++ms)
          acc[cs][ms] = __builtin_amdgcn_mfma_f32_16x16x32_bf16(X[cs], Y[kk][ms],
                                                                acc[cs][ms], 0, 0, 0);
    }
    __syncthreads();  // drains the STAGE DMA (vmcnt) + guards buffer reuse
  }

  // ---- fused epilogue ----
  const float t_new = tnew_p[0];
  const int mb = (wv << 6) + (lane & 15);
  float ctm_r[4], ftl_r[4];
  int lab_r[4];
#pragma unroll
  for (int j = 0; j < 4; ++j) {
    int m = mb + 16 * j;
    ctm_r[j] = ctm_a[m];
    ftl_r[j] = ftl_a[m];
    lab_r[j] = labels[m];
  }
  const int cq = (lane >> 4) * 4;

#pragma unroll
  for (int cs = 0; cs < 4; ++cs) {
    const int cl = cs * 16 + cq;
    const int c = c0 + cl;
    if (c >= C_DIM) continue;  // quad-granular (c%4==0, C%4==0)
    const f32x4 inv4 = *(const f32x4*)&invn_g[c0 + cl];
#pragma unroll
    for (int ms = 0; ms < 4; ++ms) {
      const int m = mb + 16 * ms;
      f32x4 a = acc[cs][ms];
      f32x4 og, ct;
#pragma unroll
      for (int r = 0; r < 4; ++r) {
        float cosv = a[r] * inv4[r];
        cosv = fminf(1.f, fmaxf(-1.f, cosv));
        og[r] = cosv * SCALE_F;
        float hard = cosv * (t_new + cosv);
        float v = (cosv > ctm_r[ms]) ? hard : cosv;
        if (c + r == lab_r[ms]) v = ftl_r[ms];
        ct[r] = v * SCALE_F;
      }
      const size_t o = (size_t)m * C_DIM + c;
      *(f32x4*)(out + o) = ct;
      *(f32x4*)(out + OUT_HALF + o) = og;
    }
  }
}

// ---------------------------------------------------------------------------
// Fallback fused kernel (R4 structure, known-correct) if ws is too small.
// ---------------------------------------------------------------------------
__global__ __launch_bounds__(512, 4) void gemm_ep_fused(
    const float* __restrict__ Kmat,
    const unsigned short* __restrict__ Asw,
    const float* __restrict__ ctm_a,
    const float* __restrict__ ftl_a,
    const float* __restrict__ tnew_p,
    const int* __restrict__ labels,
    float* __restrict__ out) {
  __shared__ unsigned short Xl[16 * 2048];
  __shared__ f32x4 ssq_sh[32][16];
  __shared__ float invn[64];

  const int tid = threadIdx.x;
  const int c0 = blockIdx.x * 64;
  const int q = tid & 15;
  const int r0 = tid >> 4;
  const int cg = c0 + q * 4;
  const bool cok = (cg < C_DIM);

  f32x4 ssq = (f32x4){0.f, 0.f, 0.f, 0.f};
  char* const wbase = (char*)&Xl[0] + (q >> 2) * 1024 + (r0 * 16 + (q & 3) * 4) * 2;
#pragma unroll
  for (int i = 0; i < 16; ++i) {
    f32x4 v = (f32x4){0.f, 0.f, 0.f, 0.f};
    if (cok)
      v = __builtin_nontemporal_load(
          (const f32x4*)(Kmat + (size_t)(r0 + 32 * i) * C_DIM + cg));
    ssq += v * v;
    i32x2 p;
    p[0] = (int)((unsigned)f2bf(v[0]) | ((unsigned)f2bf(v[1]) << 16));
    p[1] = (int)((unsigned)f2bf(v[2]) | ((unsigned)f2bf(v[3]) << 16));
    *(i32x2*)(wbase + i * 4096) = p;
  }
  ssq_sh[r0][q] = ssq;
  __syncthreads();
  if (tid < 16) {
    f32x4 ssum = (f32x4){0.f, 0.f, 0.f, 0.f};
#pragma unroll
    for (int r = 0; r < 32; ++r) ssum += ssq_sh[r][tid];
    f32x4 iv;
#pragma unroll
    for (int j = 0; j < 4; ++j) iv[j] = rsqrtf(fmaxf(ssum[j], 1e-30f));
    *(f32x4*)&invn[tid * 4] = iv;
  }
  __syncthreads();

  const int wv = tid >> 6;
  const int lane = tid & 63;

  f32x4 acc[4][4];
#pragma unroll
  for (int i = 0; i < 4; ++i)
#pragma unroll
    for (int j = 0; j < 4; ++j) acc[i][j] = (f32x4){0.f, 0.f, 0.f, 0.f};

  const unsigned ldsX = (unsigned)(uintptr_t)&Xl[0] + (unsigned)lane * 8;

#pragma unroll
  for (int s = 0; s < 16; ++s) {
    short8 Y[4];
#pragma unroll
    for (int j = 0; j < 4; ++j)
      Y[j] = *(const short8*)(Asw + (size_t)((s * 32 + wv * 4 + j) * 64 + lane) * 8);

    short8 X[4];
#pragma unroll
    for (int cs = 0; cs < 4; ++cs) {
      i32x2 t0, t1;
      unsigned a = ldsX + (unsigned)(s * 4096 + cs * 1024);
      asm volatile("ds_read_b64_tr_b16 %0, %2\n\t"
                   "ds_read_b64_tr_b16 %1, %2 offset:512"
                   : "=&v"(t0), "=&v"(t1)
                   : "v"(a));
      short4v lo = __builtin_bit_cast(short4v, t0);
      short4v hi = __builtin_bit_cast(short4v, t1);
      X[cs] = __builtin_shufflevector(lo, hi, 0, 1, 2, 3, 4, 5, 6, 7);
    }
    asm volatile("s_waitcnt lgkmcnt(0)" ::: "memory");
    __builtin_amdgcn_sched_barrier(0);

#pragma unroll
    for (int cs = 0; cs < 4; ++cs)
#pragma unroll
      for (int ms = 0; ms < 4; ++ms)
        acc[cs][ms] =
            __builtin_amdgcn_mfma_f32_16x16x32_bf16(X[cs], Y[ms], acc[cs][ms], 0, 0, 0);
  }

  const float t_new = tnew_p[0];
  const int mb = (wv << 6) + (lane & 15);
  float ctm_r[4], ftl_r[4];
  int lab_r[4];
#pragma unroll
  for (int j = 0; j < 4; ++j) {
    int m = mb + 16 * j;
    ctm_r[j] = ctm_a[m];
    ftl_r[j] = ftl_a[m];
    lab_r[j] = labels[m];
  }
  const int cq = (lane >> 4) * 4;

#pragma unroll
  for (int cs = 0; cs < 4; ++cs) {
    const int cl = cs * 16 + cq;
    const int c = c0 + cl;
    if (c >= C_DIM) continue;
    const f32x4 inv4 = *(const f32x4*)&invn[cl];
#pragma unroll
    for (int ms = 0; ms < 4; ++ms) {
      const int m = mb + 16 * ms;
      f32x4 a = acc[cs][ms];
      f32x4 og, ct;
#pragma unroll
      for (int r = 0; r < 4; ++r) {
        float cosv = a[r] * inv4[r];
        cosv = fminf(1.f, fmaxf(-1.f, cosv));
        og[r] = cosv * SCALE_F;
        float hard = cosv * (t_new + cosv);
        float v = (cosv > ctm_r[ms]) ? hard : cosv;
        if (c + r == lab_r[ms]) v = ftl_r[ms];
        ct[r] = v * SCALE_F;
      }
      const size_t o = (size_t)m * C_DIM + c;
      *(f32x4*)(out + o) = ct;
      *(f32x4*)(out + OUT_HALF + o) = og;
    }
  }
}

extern "C" void kernel_launch(void* const* d_in, const int* in_sizes, int n_in,
                              void* d_out, int out_size, void* d_ws, size_t ws_size,
                              hipStream_t stream) {
  const float* emb = (const float*)d_in[0];
  const float* Kmat = (const float*)d_in[1];
  const float* t_in = (const float*)d_in[2];
  const int* labels = (const int*)d_in[3];
  float* out = (float*)d_out;

  char* ws = (char*)d_ws;
  unsigned short* Asw = (unsigned short*)(ws + WS_ASW);
  float* target = (float*)(ws + WS_TARGET);
  float* ctm = (float*)(ws + WS_CTM);
  float* ftl = (float*)(ws + WS_FTL);
  float* tnew = (float*)(ws + WS_TNEW);

  prep_emb<<<512, 64, 0, stream>>>(emb, Asw);
  target_k<<<512, 64, 0, stream>>>(emb, Kmat, labels, target);
  rowdata_k<<<1, 512, 0, stream>>>(target, t_in, ctm, ftl, tnew);

  if (ws_size >= (size_t)WS_NEED) {
    unsigned short* Bsw = (unsigned short*)(ws + WS_BSW);
    float* invn_g = (float*)(ws + WS_INVN);
    colnorm_convert<<<391, 512, 0, stream>>>(Kmat, Bsw, invn_g);
    gemm_bsw<<<1563, 512, 0, stream>>>(Bsw, Asw, invn_g, ctm, ftl, tnew, labels, out);
  } else {
    gemm_ep_fused<<<1563, 512, 0, stream>>>(Kmat, Asw, ctm, ftl, tnew, labels, out);
  }
}